// Round 1
// baseline (371.364 us; speedup 1.0000x reference)
//
#include <hip/hip_runtime.h>
#include <hip/hip_bf16.h>

#define NB 4096

// workspace layout (bytes, all 256B-aligned)
#define XT_OFF 0u                          // 784*4096*4  = 12,845,056
#define H1_OFF 12845056u                   // 16*13*13*4096*4 = 44,302,336
#define H2_OFF 57147392u                   // 800*4096*4  = 13,107,200
#define H3_OFF 70254592u                   // 128*4096*4  =  2,097,152
// total 72,351,744 bytes

// ---------------------------------------------------------------------------
// x (4096,784) -> xT (784,4096)
__global__ __launch_bounds__(256) void k_transpose(const float* __restrict__ x,
                                                   float* __restrict__ xT) {
  __shared__ float t[32][33];
  const int c0 = blockIdx.x * 32;  // 784 dim
  const int n0 = blockIdx.y * 32;  // 4096 dim
  const int tx = threadIdx.x;      // 0..31
  const int ty = threadIdx.y;      // 0..7
  #pragma unroll
  for (int i = 0; i < 32; i += 8) {
    const int c = c0 + tx;
    if (c < 784) t[ty + i][tx] = x[(n0 + ty + i) * 784 + c];
  }
  __syncthreads();
  #pragma unroll
  for (int i = 0; i < 32; i += 8) {
    const int c = c0 + ty + i;
    if (c < 784) xT[c * NB + n0 + tx] = t[tx][ty + i];
  }
}

// ---------------------------------------------------------------------------
// LC1 + ReLU + 2x2 maxpool.  xT (28*28, N) -> h1 (16,13,13,N)
// block 256 = 16 o (hi) x 16 nlane (lo); grid (169 pos, 4 ntiles of 1024 n)
__global__ __launch_bounds__(256) void k_lc1(const float* __restrict__ xT,
                                             const float* __restrict__ w1,
                                             const float* __restrict__ b1,
                                             float* __restrict__ h1) {
  const int pos = blockIdx.x;
  const int i = pos / 13, j = pos % 13;
  const int o = threadIdx.x >> 4;
  const int nlane = threadIdx.x & 15;
  const int nbase = blockIdx.y * 1024 + nlane * 4;

  float w[4][9], bias[4];
  #pragma unroll
  for (int conv = 0; conv < 4; conv++) {
    const int y = 2 * i + (conv >> 1), x = 2 * j + (conv & 1);
    bias[conv] = b1[(o * 26 + y) * 26 + x];
    #pragma unroll
    for (int k = 0; k < 9; k++)
      w[conv][k] = w1[((o * 9 + k) * 26 + y) * 26 + x];
  }

  for (int g = 0; g < 16; g++) {  // 16 groups of 4 consecutive n
    const int n = nbase + g * 64;
    float p[16][4];
    #pragma unroll
    for (int r = 0; r < 4; r++)
      #pragma unroll
      for (int c = 0; c < 4; c++) {
        const float4 v = *reinterpret_cast<const float4*>(
            &xT[((2 * i + r) * 28 + (2 * j + c)) * NB + n]);
        p[r * 4 + c][0] = v.x; p[r * 4 + c][1] = v.y;
        p[r * 4 + c][2] = v.z; p[r * 4 + c][3] = v.w;
      }
    float rr[4];
    #pragma unroll
    for (int e = 0; e < 4; e++) {
      float best = -1e30f;
      #pragma unroll
      for (int conv = 0; conv < 4; conv++) {
        const int dy = conv >> 1, dx = conv & 1;
        float s = bias[conv];
        #pragma unroll
        for (int k = 0; k < 9; k++)
          s += w[conv][k] * p[(dy + k / 3) * 4 + (dx + k % 3)][e];
        best = fmaxf(best, s);
      }
      rr[e] = fmaxf(best, 0.f);
    }
    float4 res; res.x = rr[0]; res.y = rr[1]; res.z = rr[2]; res.w = rr[3];
    *reinterpret_cast<float4*>(&h1[((o * 13 + i) * 13 + j) * NB + n]) = res;
  }
}

// ---------------------------------------------------------------------------
// LC2 + ReLU + 2x2 maxpool.  h1 (16,13,13,N) -> h2 (800, N)  [k = o*25+i*5+j]
// block 256 = 16 o_l (hi) x 16 nlane (lo); grid (25 pos, 16 ntiles, 2 ohalf)
__global__ __launch_bounds__(256) void k_lc2(const float* __restrict__ h1,
                                             const float* __restrict__ w2,
                                             const float* __restrict__ b2,
                                             float* __restrict__ h2) {
  __shared__ float sw[16 * 16 * 36];  // [c][o_l][36]  36,864 B
  const int pos = blockIdx.x;  // 0..24
  const int i = pos / 5, j = pos % 5;
  const int ohalf = blockIdx.z;
  const int o_l = threadIdx.x >> 4;
  const int nlane = threadIdx.x & 15;
  const int o = ohalf * 16 + o_l;

  // cooperative weight slice load: w2 (32,16,9,11,11)
  for (int idx = threadIdx.x; idx < 9216; idx += 256) {
    const int c = idx / 576;
    const int r = idx % 576;
    const int ol2 = r / 36;
    const int t = r % 36;
    const int conv = t / 9, k = t % 9;
    const int y = 2 * i + (conv >> 1), x = 2 * j + (conv & 1);
    sw[idx] = w2[(((ohalf * 16 + ol2) * 16 + c) * 9 + k) * 121 + y * 11 + x];
  }
  float bias[4];
  #pragma unroll
  for (int conv = 0; conv < 4; conv++)
    bias[conv] = b2[o * 121 + (2 * i + (conv >> 1)) * 11 + (2 * j + (conv & 1))];
  __syncthreads();

  for (int pass = 0; pass < 2; pass++) {
    const int nb = blockIdx.y * 256 + pass * 128 + nlane * 4;
    float acc[2][4][4];  // [g][e][conv]
    #pragma unroll
    for (int g = 0; g < 2; g++)
      #pragma unroll
      for (int e = 0; e < 4; e++)
        #pragma unroll
        for (int conv = 0; conv < 4; conv++) acc[g][e][conv] = 0.f;

    for (int c = 0; c < 16; c++) {
      float wf[36];
      const float4* wp =
          reinterpret_cast<const float4*>(&sw[(c * 16 + o_l) * 36]);
      #pragma unroll
      for (int q = 0; q < 9; q++) {
        const float4 v = wp[q];
        wf[4 * q] = v.x; wf[4 * q + 1] = v.y;
        wf[4 * q + 2] = v.z; wf[4 * q + 3] = v.w;
      }
      #pragma unroll
      for (int g = 0; g < 2; g++) {
        float p[16][4];
        #pragma unroll
        for (int r = 0; r < 4; r++)
          #pragma unroll
          for (int cc = 0; cc < 4; cc++) {
            const float4 v = *reinterpret_cast<const float4*>(
                &h1[((c * 13 + 2 * i + r) * 13 + (2 * j + cc)) * NB + nb +
                    g * 64]);
            p[r * 4 + cc][0] = v.x; p[r * 4 + cc][1] = v.y;
            p[r * 4 + cc][2] = v.z; p[r * 4 + cc][3] = v.w;
          }
        #pragma unroll
        for (int conv = 0; conv < 4; conv++) {
          const int dy = conv >> 1, dx = conv & 1;
          #pragma unroll
          for (int k = 0; k < 9; k++) {
            const float wv = wf[conv * 9 + k];
            #pragma unroll
            for (int e = 0; e < 4; e++)
              acc[g][e][conv] += wv * p[(dy + k / 3) * 4 + (dx + k % 3)][e];
          }
        }
      }
    }
    const int ko = (o * 5 + i) * 5 + j;
    #pragma unroll
    for (int g = 0; g < 2; g++) {
      float rr[4];
      #pragma unroll
      for (int e = 0; e < 4; e++) {
        float best = -1e30f;
        #pragma unroll
        for (int conv = 0; conv < 4; conv++)
          best = fmaxf(best, acc[g][e][conv] + bias[conv]);
        rr[e] = fmaxf(best, 0.f);
      }
      float4 res; res.x = rr[0]; res.y = rr[1]; res.z = rr[2]; res.w = rr[3];
      *reinterpret_cast<float4*>(&h2[ko * NB + nb + g * 64]) = res;
    }
  }
}

// ---------------------------------------------------------------------------
// FC1 + ReLU: h2 (800,N) @ w (800,128) -> h3 (128,N)
// block 256 n; grid (16 nblocks, 16 jblocks of 8)
__global__ __launch_bounds__(256) void k_fc1(const float* __restrict__ h2,
                                             const float* __restrict__ w,
                                             const float* __restrict__ b,
                                             float* __restrict__ h3) {
  const int n = blockIdx.x * 256 + threadIdx.x;
  const int j0 = blockIdx.y * 8;
  float acc[8];
  #pragma unroll
  for (int jj = 0; jj < 8; jj++) acc[jj] = b[j0 + jj];
  for (int k = 0; k < 800; k++) {
    const float a = h2[k * NB + n];
    #pragma unroll
    for (int jj = 0; jj < 8; jj++) acc[jj] += a * w[k * 128 + j0 + jj];
  }
  #pragma unroll
  for (int jj = 0; jj < 8; jj++)
    h3[(j0 + jj) * NB + n] = fmaxf(acc[jj], 0.f);
}

// FC2: h3 (128,N) @ w (128,10) -> out (N,10)
__global__ __launch_bounds__(256) void k_fc2(const float* __restrict__ h3,
                                             const float* __restrict__ w,
                                             const float* __restrict__ b,
                                             float* __restrict__ out) {
  const int n = blockIdx.x * 256 + threadIdx.x;
  float acc[10];
  #pragma unroll
  for (int oo = 0; oo < 10; oo++) acc[oo] = b[oo];
  for (int k = 0; k < 128; k++) {
    const float a = h3[k * NB + n];
    #pragma unroll
    for (int oo = 0; oo < 10; oo++) acc[oo] += a * w[k * 10 + oo];
  }
  #pragma unroll
  for (int oo = 0; oo < 10; oo++) out[n * 10 + oo] = acc[oo];
}

// ---------------------------------------------------------------------------
extern "C" void kernel_launch(void* const* d_in, const int* in_sizes, int n_in,
                              void* d_out, int out_size, void* d_ws,
                              size_t ws_size, hipStream_t stream) {
  const float* x    = (const float*)d_in[0];
  const float* w1   = (const float*)d_in[1];
  const float* b1   = (const float*)d_in[2];
  const float* w2   = (const float*)d_in[3];
  const float* b2   = (const float*)d_in[4];
  const float* f1w  = (const float*)d_in[5];
  const float* f1b  = (const float*)d_in[6];
  const float* f2w  = (const float*)d_in[7];
  const float* f2b  = (const float*)d_in[8];
  float* out = (float*)d_out;
  char* ws = (char*)d_ws;
  float* xT = (float*)(ws + XT_OFF);
  float* h1 = (float*)(ws + H1_OFF);
  float* h2 = (float*)(ws + H2_OFF);
  float* h3 = (float*)(ws + H3_OFF);

  k_transpose<<<dim3(25, 128), dim3(32, 8), 0, stream>>>(x, xT);
  k_lc1<<<dim3(169, 4), 256, 0, stream>>>(xT, w1, b1, h1);
  k_lc2<<<dim3(25, 16, 2), 256, 0, stream>>>(h1, w2, b2, h2);
  k_fc1<<<dim3(16, 16), 256, 0, stream>>>(h2, f1w, f1b, h3);
  k_fc2<<<16, 256, 0, stream>>>(h3, f2w, f2b, out);
}

// Round 2
// 242.631 us; speedup vs baseline: 1.5306x; 1.5306x over previous
//
#include <hip/hip_runtime.h>
#include <hip/hip_bf16.h>

#define NB 4096

// workspace layout (bytes, 16B-aligned)
#define XT_OFF  0u           // 784*4096*4        = 12,845,056
#define H1_OFF  12845056u    // 16*169*4096*4     = 44,302,336
#define H2_OFF  57147392u    // 800*4096*4        = 13,107,200
#define H3_OFF  70254592u    // 128*4096*4        =  2,097,152
#define W2R_OFF 72351744u    // 25*16*4*32*12*4   =  2,457,600
// end 74,809,344

// ---------------------------------------------------------------------------
// init: h3 <- fc1 bias (pre-relu accum target), out <- fc2 bias
__global__ __launch_bounds__(256) void k_init(const float* __restrict__ f1b,
                                              const float* __restrict__ f2b,
                                              float* __restrict__ h3,
                                              float* __restrict__ out) {
  const int idx = blockIdx.x * 256 + threadIdx.x;  // 565,248 total
  if (idx < 524288) {
    h3[idx] = f1b[idx >> 12];            // h3 layout (j=128, n=4096)
  } else {
    const int r = idx - 524288;          // out (n,10)
    out[r] = f2b[r % 10];
  }
}

// ---------------------------------------------------------------------------
// x (4096,784) -> xT (784,4096)
__global__ __launch_bounds__(256) void k_transpose(const float* __restrict__ x,
                                                   float* __restrict__ xT) {
  __shared__ float t[32][33];
  const int c0 = blockIdx.x * 32;
  const int n0 = blockIdx.y * 32;
  const int tx = threadIdx.x, ty = threadIdx.y;
  #pragma unroll
  for (int i = 0; i < 32; i += 8) {
    const int c = c0 + tx;
    if (c < 784) t[ty + i][tx] = x[(n0 + ty + i) * 784 + c];
  }
  __syncthreads();
  #pragma unroll
  for (int i = 0; i < 32; i += 8) {
    const int c = c0 + ty + i;
    if (c < 784) xT[c * NB + n0 + tx] = t[tx][ty + i];
  }
}

// ---------------------------------------------------------------------------
// gather w2 (32,16,9,11,11) -> w2r [pos25][c16][conv4][o32][12pad]
__global__ __launch_bounds__(256) void k_wprep(const float* __restrict__ w2,
                                               float* __restrict__ w2r) {
  const int idx = blockIdx.x * 256 + threadIdx.x;  // 614,400 total
  const int pos = idx / 24576;
  const int r1 = idx % 24576;
  const int c = r1 / 1536;
  const int r2 = r1 % 1536;
  const int conv = r2 / 384;
  const int r3 = r2 % 384;
  const int o = r3 / 12;
  const int k = r3 % 12;
  float v = 0.f;
  if (k < 9) {
    const int i = pos / 5, j = pos % 5;
    const int y = 2 * i + (conv >> 1), x = 2 * j + (conv & 1);
    v = w2[((o * 16 + c) * 9 + k) * 121 + y * 11 + x];
  }
  w2r[idx] = v;
}

// ---------------------------------------------------------------------------
// LC1 + ReLU + pool.  xT (784,N) -> h1 (16,13,13,N)
// block 256 = 4 og (4 o each, one wave) x 64 nl (4 n each); grid (169, 16)
__global__ __launch_bounds__(256, 3) void k_lc1(const float* __restrict__ xT,
                                                const float* __restrict__ w1,
                                                const float* __restrict__ b1,
                                                float* __restrict__ h1) {
  __shared__ __align__(16) float sw[640];  // [o16][36] weights + [576..] bias[o][conv]
  const int pos = blockIdx.x;
  const int i = pos / 13, j = pos % 13;
  const int tid = threadIdx.x;
  const int og = tid >> 6, nl = tid & 63;
  const int o0 = og * 4;
  const int n = blockIdx.y * 256 + nl * 4;

  // cooperative stage of weights+bias for this pos
  for (int idx = tid; idx < 640; idx += 256) {
    float v;
    if (idx < 576) {
      const int o = idx / 36, t = idx % 36;
      const int cv = t / 9, k = t % 9;
      const int y = 2 * i + (cv >> 1), x = 2 * j + (cv & 1);
      v = w1[(o * 9 + k) * 676 + y * 26 + x];
    } else {
      const int r = idx - 576;
      const int o = r >> 2, cv = r & 3;
      v = b1[(o * 26 + 2 * i + (cv >> 1)) * 26 + 2 * j + (cv & 1)];
    }
    sw[idx] = v;
  }
  __syncthreads();

  // patches 4x4 x 4n
  float p[16][4];
  #pragma unroll
  for (int r = 0; r < 4; r++)
    #pragma unroll
    for (int cc = 0; cc < 4; cc++) {
      const float4 v = *reinterpret_cast<const float4*>(
          &xT[((2 * i + r) * 28 + (2 * j + cc)) * NB + n]);
      p[r * 4 + cc][0] = v.x; p[r * 4 + cc][1] = v.y;
      p[r * 4 + cc][2] = v.z; p[r * 4 + cc][3] = v.w;
    }

  #pragma unroll
  for (int ot = 0; ot < 4; ot++) {
    const int o = o0 + ot;
    float wf[36];
    const float4* wp = reinterpret_cast<const float4*>(&sw[o * 36]);
    #pragma unroll
    for (int q = 0; q < 9; q++) {
      const float4 v = wp[q];
      wf[4 * q] = v.x; wf[4 * q + 1] = v.y;
      wf[4 * q + 2] = v.z; wf[4 * q + 3] = v.w;
    }
    float s[4][4];
    #pragma unroll
    for (int cv = 0; cv < 4; cv++)
      #pragma unroll
      for (int e = 0; e < 4; e++) s[cv][e] = 0.f;
    #pragma unroll
    for (int cv = 0; cv < 4; cv++) {
      const int dy = cv >> 1, dx = cv & 1;
      #pragma unroll
      for (int k = 0; k < 9; k++) {
        const float wv = wf[cv * 9 + k];
        #pragma unroll
        for (int e = 0; e < 4; e++)
          s[cv][e] += wv * p[(dy + k / 3) * 4 + (dx + k % 3)][e];
      }
    }
    float rr[4];
    #pragma unroll
    for (int e = 0; e < 4; e++) {
      float best = -1e30f;
      #pragma unroll
      for (int cv = 0; cv < 4; cv++)
        best = fmaxf(best, s[cv][e] + sw[576 + o * 4 + cv]);
      rr[e] = fmaxf(best, 0.f);
    }
    float4 res; res.x = rr[0]; res.y = rr[1]; res.z = rr[2]; res.w = rr[3];
    *reinterpret_cast<float4*>(&h1[((o * 13 + i) * 13 + j) * NB + n]) = res;
  }
}

// ---------------------------------------------------------------------------
// LC2 + ReLU + pool.  h1 (16,13,13,N) -> h2 (800,N)  k = o*25+i*5+j
// block 256 = 8 og (4 o each) x 32 nl (4 n each); grid (25 pos, 32 ntiles)
__global__ __launch_bounds__(256, 3) void k_lc2(const float* __restrict__ h1,
                                                const float* __restrict__ w2r,
                                                const float* __restrict__ b2,
                                                float* __restrict__ h2) {
  __shared__ float4 swb[2][384];  // per-c weights [conv4][o32][12pad], dbuf
  const int pos = blockIdx.x;
  const int i = pos / 5, j = pos % 5;
  const int tid = threadIdx.x;
  const int og = tid >> 5, nl = tid & 31;
  const int o0 = og * 4;
  const int n = blockIdx.y * 128 + nl * 4;
  const float4* wsrc = reinterpret_cast<const float4*>(w2r + pos * 24576);

  // stage c=0
  swb[0][tid] = wsrc[tid];
  if (tid < 128) swb[0][256 + tid] = wsrc[256 + tid];
  __syncthreads();

  float acc[4][4][4];  // [ot][conv][e]
  #pragma unroll
  for (int ot = 0; ot < 4; ot++)
    #pragma unroll
    for (int cv = 0; cv < 4; cv++)
      #pragma unroll
      for (int e = 0; e < 4; e++) acc[ot][cv][e] = 0.f;

  for (int c = 0; c < 16; c++) {
    const int b = c & 1;
    // prefetch next c's weights into the other buffer (early, frees regs)
    if (c < 15) {
      const float4* s = wsrc + (c + 1) * 384;
      const float4 p0 = s[tid];
      swb[b ^ 1][tid] = p0;
      if (tid < 128) {
        const float4 p1 = s[256 + tid];
        swb[b ^ 1][256 + tid] = p1;
      }
    }
    // patches 4x4 x 4n (addresses og-independent -> wave-dedup'd in L1)
    float p[16][4];
    #pragma unroll
    for (int r = 0; r < 4; r++)
      #pragma unroll
      for (int cc = 0; cc < 4; cc++) {
        const float4 v = *reinterpret_cast<const float4*>(
            &h1[((c * 13 + 2 * i + r) * 13 + (2 * j + cc)) * NB + n]);
        p[r * 4 + cc][0] = v.x; p[r * 4 + cc][1] = v.y;
        p[r * 4 + cc][2] = v.z; p[r * 4 + cc][3] = v.w;
      }
    #pragma unroll
    for (int ot = 0; ot < 4; ot++) {
      const int o = o0 + ot;
      #pragma unroll
      for (int cv = 0; cv < 4; cv++) {
        const float4* wb = &swb[b][(cv * 32 + o) * 3];
        const float4 q0 = wb[0], q1 = wb[1], q2 = wb[2];
        const float wf[9] = {q0.x, q0.y, q0.z, q0.w, q1.x, q1.y, q1.z, q1.w, q2.x};
        const int dy = cv >> 1, dx = cv & 1;
        #pragma unroll
        for (int k = 0; k < 9; k++) {
          const float wv = wf[k];
          #pragma unroll
          for (int e = 0; e < 4; e++)
            acc[ot][cv][e] += wv * p[(dy + k / 3) * 4 + (dx + k % 3)][e];
        }
      }
    }
    __syncthreads();
  }

  #pragma unroll
  for (int ot = 0; ot < 4; ot++) {
    const int o = o0 + ot;
    float bias[4];
    #pragma unroll
    for (int cv = 0; cv < 4; cv++)
      bias[cv] = b2[o * 121 + (2 * i + (cv >> 1)) * 11 + (2 * j + (cv & 1))];
    float rr[4];
    #pragma unroll
    for (int e = 0; e < 4; e++) {
      float best = -1e30f;
      #pragma unroll
      for (int cv = 0; cv < 4; cv++)
        best = fmaxf(best, acc[ot][cv][e] + bias[cv]);
      rr[e] = fmaxf(best, 0.f);
    }
    const int ko = (o * 5 + i) * 5 + j;
    float4 res; res.x = rr[0]; res.y = rr[1]; res.z = rr[2]; res.w = rr[3];
    *reinterpret_cast<float4*>(&h2[ko * NB + n]) = res;
  }
}

// ---------------------------------------------------------------------------
// FC1 partial: h2 (800,N) @ w (800,128), split-K=4, atomicAdd into h3 (128,N)
// h3 pre-initialized with bias; relu deferred to fc2. grid (16 nt, 4 jt, 4 ks)
__global__ __launch_bounds__(256) void k_fc1(const float* __restrict__ h2,
                                             const float* __restrict__ w,
                                             float* __restrict__ h3) {
  __shared__ __align__(16) float4 wls[1600];  // 200k x 32j
  const int n = blockIdx.x * 256 + threadIdx.x;
  const int j0 = blockIdx.y * 32;
  const int k0 = blockIdx.z * 200;
  for (int idx = threadIdx.x; idx < 1600; idx += 256) {
    const int kk = idx >> 3, f = idx & 7;
    wls[idx] = reinterpret_cast<const float4*>(w + (k0 + kk) * 128 + j0)[f];
  }
  __syncthreads();
  float acc[32];
  #pragma unroll
  for (int jj = 0; jj < 32; jj++) acc[jj] = 0.f;
  for (int kk = 0; kk < 200; kk++) {
    const float a = h2[(k0 + kk) * NB + n];
    const float4* wr = &wls[kk * 8];
    #pragma unroll
    for (int f = 0; f < 8; f++) {
      const float4 v = wr[f];
      acc[f * 4 + 0] += a * v.x;
      acc[f * 4 + 1] += a * v.y;
      acc[f * 4 + 2] += a * v.z;
      acc[f * 4 + 3] += a * v.w;
    }
  }
  #pragma unroll
  for (int jj = 0; jj < 32; jj++)
    atomicAdd(&h3[(j0 + jj) * NB + n], acc[jj]);
}

// ---------------------------------------------------------------------------
// FC2: relu(h3) (128,N) @ w (128,10), split-K=2, atomicAdd into out (N,10)
// out pre-initialized with bias. grid (16 nt, 2 ks)
__global__ __launch_bounds__(256) void k_fc2(const float* __restrict__ h3,
                                             const float* __restrict__ w,
                                             float* __restrict__ out) {
  __shared__ __align__(16) float wf2[768];  // 64k x 12pad
  const int n = blockIdx.x * 256 + threadIdx.x;
  const int k0 = blockIdx.y * 64;
  for (int idx = threadIdx.x; idx < 768; idx += 256) {
    const int kk = idx / 12, f = idx % 12;
    wf2[idx] = (f < 10) ? w[(k0 + kk) * 10 + f] : 0.f;
  }
  __syncthreads();
  float acc[10];
  #pragma unroll
  for (int oo = 0; oo < 10; oo++) acc[oo] = 0.f;
  for (int kk = 0; kk < 64; kk++) {
    const float a = fmaxf(h3[(k0 + kk) * NB + n], 0.f);
    const float4* wr = reinterpret_cast<const float4*>(&wf2[kk * 12]);
    const float4 v0 = wr[0], v1 = wr[1];
    const float2 v2 = *reinterpret_cast<const float2*>(&wf2[kk * 12 + 8]);
    acc[0] += a * v0.x; acc[1] += a * v0.y; acc[2] += a * v0.z; acc[3] += a * v0.w;
    acc[4] += a * v1.x; acc[5] += a * v1.y; acc[6] += a * v1.z; acc[7] += a * v1.w;
    acc[8] += a * v2.x; acc[9] += a * v2.y;
  }
  #pragma unroll
  for (int oo = 0; oo < 10; oo++) atomicAdd(&out[n * 10 + oo], acc[oo]);
}

// ---------------------------------------------------------------------------
extern "C" void kernel_launch(void* const* d_in, const int* in_sizes, int n_in,
                              void* d_out, int out_size, void* d_ws,
                              size_t ws_size, hipStream_t stream) {
  const float* x   = (const float*)d_in[0];
  const float* w1  = (const float*)d_in[1];
  const float* b1  = (const float*)d_in[2];
  const float* w2  = (const float*)d_in[3];
  const float* b2  = (const float*)d_in[4];
  const float* f1w = (const float*)d_in[5];
  const float* f1b = (const float*)d_in[6];
  const float* f2w = (const float*)d_in[7];
  const float* f2b = (const float*)d_in[8];
  float* out = (float*)d_out;
  char* ws = (char*)d_ws;
  float* xT  = (float*)(ws + XT_OFF);
  float* h1  = (float*)(ws + H1_OFF);
  float* h2  = (float*)(ws + H2_OFF);
  float* h3  = (float*)(ws + H3_OFF);
  float* w2r = (float*)(ws + W2R_OFF);

  k_init<<<2208, 256, 0, stream>>>(f1b, f2b, h3, out);
  k_transpose<<<dim3(25, 128), dim3(32, 8), 0, stream>>>(x, xT);
  k_wprep<<<2400, 256, 0, stream>>>(w2, w2r);
  k_lc1<<<dim3(169, 16), 256, 0, stream>>>(xT, w1, b1, h1);
  k_lc2<<<dim3(25, 32), 256, 0, stream>>>(h1, w2r, b2, h2);
  k_fc1<<<dim3(16, 4, 4), 256, 0, stream>>>(h2, f1w, h3);
  k_fc2<<<dim3(16, 2), 256, 0, stream>>>(h3, f2w, out);
}